// Round 3
// baseline (151.858 us; speedup 1.0000x reference)
//
#include <hip/hip_runtime.h>
#include <hip/hip_bf16.h>

#define B_ 4
#define L_ 1024
#define E_ 256
#define S_ 32

typedef __bf16 bf16x8 __attribute__((ext_vector_type(8)));
typedef float f32x4 __attribute__((ext_vector_type(4)));

// ===========================================================================
// PATH A (needs >= 12.6 MB workspace): 2-kernel fp32-QKV pipeline.
// Inputs are fp32 (per reference). GEMM uses MFMA bf16 with hi/lo split:
// a = ah + al (ah = bf16(a), al = bf16(a - ah));  A*B ~= ah*bh + ah*bl + al*bh
// (lo*lo term ~2^-18 rel, dropped). fp32 accumulate -> ~1e-4 rel accuracy.
// ===========================================================================

// out[m,n] = sum_k A[m,k] * W[n,k] + bias[n]
// MFMA 16x16x32 bf16: A-op A[m=lane&15][k=(lane>>4)*8+j];
//                     B-op B[n=lane&15][k=(lane>>4)*8+j] (W is [n,k] row-major);
//                     C/D  col(n)=lane&15, row(m)=(lane>>4)*4+reg.
__global__ __launch_bounds__(256) void qkv_gemm(
    const float* __restrict__ A,
    const float* __restrict__ Wq, const float* __restrict__ bq,
    const float* __restrict__ Wk, const float* __restrict__ bk,
    const float* __restrict__ Wv, const float* __restrict__ bv,
    float* __restrict__ Qo, float* __restrict__ Ko, float* __restrict__ Vo)
{
    const float* Wm;
    const float* bm;
    float* Om;
    const int z = blockIdx.z;
    if (z == 0)      { Wm = Wq; bm = bq; Om = Qo; }
    else if (z == 1) { Wm = Wk; bm = bk; Om = Ko; }
    else             { Wm = Wv; bm = bv; Om = Vo; }

    const int wave = threadIdx.x >> 6;
    const int lane = threadIdx.x & 63;
    const int m0 = blockIdx.x * 16;
    const int n0 = blockIdx.y * 64 + wave * 16;

    const int rsel = lane & 15;
    const int koff = (lane >> 4) * 8;

    const float* pa = A  + (size_t)(m0 + rsel) * 256 + koff;
    const float* pw = Wm + (size_t)(n0 + rsel) * 256 + koff;

    f32x4 acc = {0.f, 0.f, 0.f, 0.f};
#pragma unroll
    for (int k0 = 0; k0 < 256; k0 += 32) {
        const float4 a0 = *(const float4*)(pa + k0);
        const float4 a1 = *(const float4*)(pa + k0 + 4);
        const float4 w0 = *(const float4*)(pw + k0);
        const float4 w1 = *(const float4*)(pw + k0 + 4);
        const float av[8] = {a0.x, a0.y, a0.z, a0.w, a1.x, a1.y, a1.z, a1.w};
        const float wv[8] = {w0.x, w0.y, w0.z, w0.w, w1.x, w1.y, w1.z, w1.w};
        bf16x8 ah, al, bh, bl;
#pragma unroll
        for (int j = 0; j < 8; ++j) {
            __bf16 h = (__bf16)av[j];
            ah[j] = h;
            al[j] = (__bf16)(av[j] - (float)h);
            h = (__bf16)wv[j];
            bh[j] = h;
            bl[j] = (__bf16)(wv[j] - (float)h);
        }
        acc = __builtin_amdgcn_mfma_f32_16x16x32_bf16(ah, bh, acc, 0, 0, 0);
        acc = __builtin_amdgcn_mfma_f32_16x16x32_bf16(ah, bl, acc, 0, 0, 0);
        acc = __builtin_amdgcn_mfma_f32_16x16x32_bf16(al, bh, acc, 0, 0, 0);
    }

    const int n = n0 + rsel;
    const float bias = bm[n];
    const int mrow = m0 + (lane >> 4) * 4;
#pragma unroll
    for (int r = 0; r < 4; ++r)
        Om[(size_t)(mrow + r) * 256 + n] = acc[r] + bias;
}

// Windowed per-channel softmax + context + sigmoid^2 epilogue (all fp32).
__global__ __launch_bounds__(256) void aft_stage2(
    const float* __restrict__ Q, const float* __restrict__ K,
    const float* __restrict__ V, const float* __restrict__ pb,
    float* __restrict__ out)
{
    const int t = threadIdx.x;
    const int c4 = (t & 63) * 4;
    const int isub = t >> 6;
    const int b = blockIdx.y;
    const int i = blockIdx.x * 4 + isub;

    const size_t rowQ = ((size_t)b * L_ + i) * E_;
    const float* Kb = K + (size_t)b * L_ * E_;
    const float* Vb = V + (size_t)b * L_ * E_;

    const float4 qv = *(const float4*)(Q + rowQ + c4);

    float den0 = 0.f, den1 = 0.f, den2 = 0.f, den3 = 0.f;
    float num0 = 0.f, num1 = 0.f, num2 = 0.f, num3 = 0.f;

    const int jlo = (i - S_ < 0) ? 0 : (i - S_);
    const int jhi = (i + S_ > L_ - 1) ? (L_ - 1) : (i + S_);

    for (int j = jlo; j <= jhi; ++j) {
        const int w = j - i + S_;
        const float4 vv = *(const float4*)(Vb + (size_t)j * E_ + c4);

        float kx = 0.f, ky = 0.f, kz = 0.f, kw = 0.f;
        if (w != 0 && w != 2 * S_) {           // strict |rel| < S mask
            const float4 kk = *(const float4*)(Kb + (size_t)j * E_ + c4);
            const float4 pp = *(const float4*)(pb + (size_t)w * E_ + c4);
            kx = kk.x + pp.x;
            ky = kk.y + pp.y;
            kz = kk.z + pp.z;
            kw = kk.w + pp.w;
        }
        const float e0 = __expf(qv.x * kx);
        const float e1 = __expf(qv.y * ky);
        const float e2 = __expf(qv.z * kz);
        const float e3 = __expf(qv.w * kw);
        den0 += e0; den1 += e1; den2 += e2; den3 += e3;
        num0 += e0 * vv.x; num1 += e1 * vv.y;
        num2 += e2 * vv.z; num3 += e3 * vv.w;
    }

    const float s0 = 1.f / (1.f + __expf(-qv.x));
    const float s1 = 1.f / (1.f + __expf(-qv.y));
    const float s2 = 1.f / (1.f + __expf(-qv.z));
    const float s3 = 1.f / (1.f + __expf(-qv.w));

    float4 o;
    o.x = s0 * s0 * num0 / den0;
    o.y = s1 * s1 * num1 / den1;
    o.z = s2 * s2 * num2 / den2;
    o.w = s3 * s3 * num3 / den3;
    *(float4*)(out + rowQ + c4) = o;
}

// ===========================================================================
// PATH B (zero workspace): fully fused. Block = (32 i-rows, 64 channels) for
// one batch. Phase 1: MFMA projections (Q 32 rows, K/V 96-row halo) -> LDS.
// Phase 2: windowed softmax from LDS.
// ===========================================================================
#define TI 32
#define CG 64
#define RK 96          // TI + 2*S halo rows for K/V
#define LDP 68         // padded LDS stride in floats

__global__ __launch_bounds__(256) void aft_fused(
    const float* __restrict__ q,
    const float* __restrict__ Wq, const float* __restrict__ bq,
    const float* __restrict__ Wk, const float* __restrict__ bk,
    const float* __restrict__ Wv, const float* __restrict__ bv,
    const float* __restrict__ pb,
    float* __restrict__ out)
{
    __shared__ float Kl[RK][LDP];
    __shared__ float Vl[RK][LDP];
    __shared__ float Ql[TI][LDP];

    const int i0 = blockIdx.x * TI;
    const int b  = blockIdx.y;
    const int c0 = blockIdx.z * CG;

    const int wave = threadIdx.x >> 6;
    const int lane = threadIdx.x & 63;
    const int rsel = lane & 15;
    const int koff = (lane >> 4) * 8;

    const float* qb = q + (size_t)b * L_ * E_;

    // ---- Phase 1: 56 MFMA tile-jobs (K:24, V:24, Q:8), 14 per wave ----
    for (int job = wave; job < 56; job += 4) {
        int p, rt, ct;
        if (job < 24)      { p = 0; rt = job >> 2;        ct = job & 3; }
        else if (job < 48) { p = 1; rt = (job - 24) >> 2; ct = (job - 24) & 3; }
        else               { p = 2; rt = (job - 48) >> 2; ct = (job - 48) & 3; }

        int jrow = (p == 2) ? (i0 + rt * 16 + rsel)
                            : (i0 - S_ + rt * 16 + rsel);
        int jc = jrow < 0 ? 0 : (jrow > L_ - 1 ? L_ - 1 : jrow); // clamp; OOB rows never read back
        const float* pa = qb + (size_t)jc * E_ + koff;

        const float* Wm = (p == 0) ? Wk : (p == 1) ? Wv : Wq;
        const float* bm = (p == 0) ? bk : (p == 1) ? bv : bq;
        const int n = c0 + ct * 16 + rsel;
        const float* pw = Wm + (size_t)n * E_ + koff;

        f32x4 acc = {0.f, 0.f, 0.f, 0.f};
#pragma unroll
        for (int k0 = 0; k0 < 256; k0 += 32) {
            const float4 a0 = *(const float4*)(pa + k0);
            const float4 a1 = *(const float4*)(pa + k0 + 4);
            const float4 w0 = *(const float4*)(pw + k0);
            const float4 w1 = *(const float4*)(pw + k0 + 4);
            const float av[8] = {a0.x, a0.y, a0.z, a0.w, a1.x, a1.y, a1.z, a1.w};
            const float wv[8] = {w0.x, w0.y, w0.z, w0.w, w1.x, w1.y, w1.z, w1.w};
            bf16x8 ah, al, bh, bl;
#pragma unroll
            for (int j = 0; j < 8; ++j) {
                __bf16 h = (__bf16)av[j];
                ah[j] = h;
                al[j] = (__bf16)(av[j] - (float)h);
                h = (__bf16)wv[j];
                bh[j] = h;
                bl[j] = (__bf16)(wv[j] - (float)h);
            }
            acc = __builtin_amdgcn_mfma_f32_16x16x32_bf16(ah, bh, acc, 0, 0, 0);
            acc = __builtin_amdgcn_mfma_f32_16x16x32_bf16(ah, bl, acc, 0, 0, 0);
            acc = __builtin_amdgcn_mfma_f32_16x16x32_bf16(al, bh, acc, 0, 0, 0);
        }

        const float bias = bm[n];
        const int row0 = rt * 16 + (lane >> 4) * 4;
        const int colc = ct * 16 + rsel;
        float* dst = (p == 0) ? &Kl[0][0] : (p == 1) ? &Vl[0][0] : &Ql[0][0];
#pragma unroll
        for (int r = 0; r < 4; ++r)
            dst[(size_t)(row0 + r) * LDP + colc] = acc[r] + bias;
    }
    __syncthreads();

    // ---- Phase 2: per-channel window softmax ----
    const int cq  = threadIdx.x & 15;   // channel quad 0..15
    const int is0 = threadIdx.x >> 4;   // 0..15
    const int cL  = cq * 4;
    const int cG  = c0 + cL;
    const float* pbc = pb + cG;

    for (int rr = is0; rr < TI; rr += 16) {
        const int i = i0 + rr;
        const float4 qv = *(const float4*)&Ql[rr][cL];

        float den0 = 0.f, den1 = 0.f, den2 = 0.f, den3 = 0.f;
        float num0 = 0.f, num1 = 0.f, num2 = 0.f, num3 = 0.f;

        const int jlo = (i - S_ < 0) ? 0 : (i - S_);
        const int jhi = (i + S_ > L_ - 1) ? (L_ - 1) : (i + S_);

        for (int j = jlo; j <= jhi; ++j) {
            const int r = j - (i0 - S_);        // 0..95
            const int w = j - i + S_;
            const float4 vv = *(const float4*)&Vl[r][cL];

            float kx = 0.f, ky = 0.f, kz = 0.f, kw = 0.f;
            if (w != 0 && w != 2 * S_) {
                const float4 kk = *(const float4*)&Kl[r][cL];
                const float4 pp = *(const float4*)(pbc + (size_t)w * E_);
                kx = kk.x + pp.x;
                ky = kk.y + pp.y;
                kz = kk.z + pp.z;
                kw = kk.w + pp.w;
            }
            const float e0 = __expf(qv.x * kx);
            const float e1 = __expf(qv.y * ky);
            const float e2 = __expf(qv.z * kz);
            const float e3 = __expf(qv.w * kw);
            den0 += e0; den1 += e1; den2 += e2; den3 += e3;
            num0 += e0 * vv.x; num1 += e1 * vv.y;
            num2 += e2 * vv.z; num3 += e3 * vv.w;
        }

        const float s0 = 1.f / (1.f + __expf(-qv.x));
        const float s1 = 1.f / (1.f + __expf(-qv.y));
        const float s2 = 1.f / (1.f + __expf(-qv.z));
        const float s3 = 1.f / (1.f + __expf(-qv.w));

        float4 o;
        o.x = s0 * s0 * num0 / den0;
        o.y = s1 * s1 * num1 / den1;
        o.z = s2 * s2 * num2 / den2;
        o.w = s3 * s3 * num3 / den3;
        *(float4*)(out + ((size_t)b * L_ + i) * E_ + cG) = o;
    }
}

extern "C" void kernel_launch(void* const* d_in, const int* in_sizes, int n_in,
                              void* d_out, int out_size, void* d_ws, size_t ws_size,
                              hipStream_t stream) {
    const float* q  = (const float*)d_in[0];
    const float* Wq = (const float*)d_in[1];
    const float* bq = (const float*)d_in[2];
    const float* Wk = (const float*)d_in[3];
    const float* bk = (const float*)d_in[4];
    const float* Wv = (const float*)d_in[5];
    const float* bv = (const float*)d_in[6];
    const float* pb = (const float*)d_in[7];

    const size_t needA = (size_t)3 * 4096 * 256 * sizeof(float);  // 12.6 MB

    if (ws_size >= needA) {
        float* Qf = (float*)d_ws;
        float* Kf = Qf + (size_t)4096 * 256;
        float* Vf = Kf + (size_t)4096 * 256;
        qkv_gemm<<<dim3(256, 4, 3), 256, 0, stream>>>(q, Wq, bq, Wk, bk, Wv, bv,
                                                      Qf, Kf, Vf);
        aft_stage2<<<dim3(L_ / 4, B_), 256, 0, stream>>>(Qf, Kf, Vf, pb,
                                                         (float*)d_out);
    } else {
        aft_fused<<<dim3(L_ / TI, B_, E_ / CG), 256, 0, stream>>>(
            q, Wq, bq, Wk, bk, Wv, bv, pb, (float*)d_out);
    }
}

// Round 4
// 123.642 us; speedup vs baseline: 1.2282x; 1.2282x over previous
//
#include <hip/hip_runtime.h>
#include <hip/hip_bf16.h>

#define B_ 4
#define L_ 1024
#define E_ 256
#define S_ 32

typedef __bf16 bf16x8 __attribute__((ext_vector_type(8)));
typedef float f32x4 __attribute__((ext_vector_type(4)));

__device__ __forceinline__ __bf16 bf_from_bits(unsigned short u) {
    __bf16 b;
    __builtin_memcpy(&b, &u, 2);
    return b;
}

// Split fp32 -> bf16 hi (truncate) + bf16 lo (residual). a ~= hi + lo with
// ~2^-17 rel error when both terms are used in the MFMA product expansion.
__device__ __forceinline__ void load8split(const float* __restrict__ p,
                                           bf16x8& h, bf16x8& l) {
    const float4 x0 = *(const float4*)p;
    const float4 x1 = *(const float4*)(p + 4);
    const float xs[8] = {x0.x, x0.y, x0.z, x0.w, x1.x, x1.y, x1.z, x1.w};
#pragma unroll
    for (int j = 0; j < 8; ++j) {
        const unsigned hb = __float_as_uint(xs[j]) & 0xFFFF0000u;
        h[j] = bf_from_bits((unsigned short)(hb >> 16));
        l[j] = (__bf16)(xs[j] - __uint_as_float(hb));
    }
}

// ===========================================================================
// PATH A kernel 1: Q/K/V projections, out[m,n] = sum_k A[m,k]*W[n,k] + b[n].
// Block 256 = 4 waves; block slab = 32 rows x 256 cols (one matrix, z-dim).
// Wave: 2 M-tiles x 4 N-tiles (8 accumulators) -> 24 MFMA per 6 fragment
// loads per K-step; launch_bounds(256,1) lets the unrolled loop keep loads
// in flight (round-3 version was latency-bound at 20 VGPRs, MfmaUtil 3%).
// MFMA 16x16x32 bf16 mapping (verified round 3): A-op A[m=lane&15][k=(lane>>4)*8+j];
// B-op W[n=lane&15][k=...]; C/D col(n)=lane&15, row(m)=(lane>>4)*4+reg.
// ===========================================================================
__global__ __launch_bounds__(256, 1) void qkv_gemm2(
    const float* __restrict__ A,
    const float* __restrict__ Wq, const float* __restrict__ bq,
    const float* __restrict__ Wk, const float* __restrict__ bk,
    const float* __restrict__ Wv, const float* __restrict__ bv,
    float* __restrict__ Qo, float* __restrict__ Ko, float* __restrict__ Vo)
{
    const float* Wm;
    const float* bm;
    float* Om;
    const int z = blockIdx.z;
    if (z == 0)      { Wm = Wq; bm = bq; Om = Qo; }
    else if (z == 1) { Wm = Wk; bm = bk; Om = Ko; }
    else             { Wm = Wv; bm = bv; Om = Vo; }

    const int wave = threadIdx.x >> 6;
    const int lane = threadIdx.x & 63;
    const int rsel = lane & 15;
    const int koff = (lane >> 4) * 8;

    const int m0 = blockIdx.x * 32;
    const int nb = wave * 64;

    const float* pa0 = A + (size_t)(m0 + rsel) * 256 + koff;
    const float* pa1 = pa0 + (size_t)16 * 256;
    const float* pw0 = Wm + (size_t)(nb + 0  + rsel) * 256 + koff;
    const float* pw1 = Wm + (size_t)(nb + 16 + rsel) * 256 + koff;
    const float* pw2 = Wm + (size_t)(nb + 32 + rsel) * 256 + koff;
    const float* pw3 = Wm + (size_t)(nb + 48 + rsel) * 256 + koff;

    f32x4 acc[2][4];
#pragma unroll
    for (int mt = 0; mt < 2; ++mt)
#pragma unroll
        for (int nt = 0; nt < 4; ++nt)
            acc[mt][nt] = (f32x4){0.f, 0.f, 0.f, 0.f};

#pragma unroll
    for (int k0 = 0; k0 < 256; k0 += 32) {
        bf16x8 ah[2], al[2], bh[4], bl[4];
        load8split(pa0 + k0, ah[0], al[0]);
        load8split(pa1 + k0, ah[1], al[1]);
        load8split(pw0 + k0, bh[0], bl[0]);
        load8split(pw1 + k0, bh[1], bl[1]);
        load8split(pw2 + k0, bh[2], bl[2]);
        load8split(pw3 + k0, bh[3], bl[3]);
#pragma unroll
        for (int mt = 0; mt < 2; ++mt)
#pragma unroll
            for (int nt = 0; nt < 4; ++nt) {
                acc[mt][nt] = __builtin_amdgcn_mfma_f32_16x16x32_bf16(
                    ah[mt], bh[nt], acc[mt][nt], 0, 0, 0);
                acc[mt][nt] = __builtin_amdgcn_mfma_f32_16x16x32_bf16(
                    ah[mt], bl[nt], acc[mt][nt], 0, 0, 0);
                acc[mt][nt] = __builtin_amdgcn_mfma_f32_16x16x32_bf16(
                    al[mt], bh[nt], acc[mt][nt], 0, 0, 0);
            }
    }

#pragma unroll
    for (int mt = 0; mt < 2; ++mt) {
        const int mrow = m0 + mt * 16 + (lane >> 4) * 4;
#pragma unroll
        for (int nt = 0; nt < 4; ++nt) {
            const int n = nb + nt * 16 + rsel;
            const float bias = bm[n];
#pragma unroll
            for (int r = 0; r < 4; ++r)
                Om[(size_t)(mrow + r) * 256 + n] = acc[mt][nt][r] + bias;
        }
    }
}

// ===========================================================================
// PATH A kernel 2: windowed per-channel softmax + context + sigmoid^2.
// Block = 32 i-rows x 64 channels for one batch. K/V halo (96 rows) and the
// pos_bias slice (65 rows) are staged in LDS (stride 68 floats; 272 B is
// 16B-aligned and rotates banks by 4), then each thread computes 2 rows x
// 65 taps from LDS. Round-3 version re-read ~820 MB from L2.
// ===========================================================================
#define TI2 32
#define CH2 64
#define HB2 96          // TI2 + 2*S halo rows
#define PS2 68          // padded LDS stride (floats)

__global__ __launch_bounds__(256) void aft_stage2b(
    const float* __restrict__ Q, const float* __restrict__ K,
    const float* __restrict__ V, const float* __restrict__ pb,
    float* __restrict__ out)
{
    __shared__ float Kw[HB2][PS2];   // 26112 B
    __shared__ float Vw[HB2][PS2];   // 26112 B
    __shared__ float Pw[2 * S_ + 1][PS2]; // 17680 B  (total ~70 KB)

    const int tid = threadIdx.x;
    const int b  = blockIdx.y;
    const int i0 = blockIdx.x * TI2;
    const int c0 = blockIdx.z * CH2;

    const float* Kb = K + (size_t)b * L_ * E_;
    const float* Vb = V + (size_t)b * L_ * E_;

    // ---- stage K/V halo rows ----
    for (int idx = tid; idx < HB2 * 16; idx += 256) {
        const int r  = idx >> 4;
        const int cq = (idx & 15) * 4;
        int j = i0 - S_ + r;
        j = j < 0 ? 0 : (j > L_ - 1 ? L_ - 1 : j);   // clamped rows never used
        const size_t g = (size_t)j * E_ + c0 + cq;
        *(float4*)&Kw[r][cq] = *(const float4*)(Kb + g);
        *(float4*)&Vw[r][cq] = *(const float4*)(Vb + g);
    }
    // ---- stage pos_bias slice ----
    for (int idx = tid; idx < (2 * S_ + 1) * 16; idx += 256) {
        const int r  = idx >> 4;
        const int cq = (idx & 15) * 4;
        *(float4*)&Pw[r][cq] = *(const float4*)(pb + (size_t)r * E_ + c0 + cq);
    }
    __syncthreads();

    const int cq = (tid & 15) * 4;   // channel quad within block
    const int is = tid >> 4;         // 0..15

#pragma unroll
    for (int rep = 0; rep < 2; ++rep) {
        const int rr = is + rep * 16;         // 0..31
        const int i  = i0 + rr;

        const float4 qv = *(const float4*)(Q + ((size_t)b * L_ + i) * E_ + c0 + cq);

        float den0 = 0.f, den1 = 0.f, den2 = 0.f, den3 = 0.f;
        float num0 = 0.f, num1 = 0.f, num2 = 0.f, num3 = 0.f;

        const int jlo = (i - S_ < 0) ? 0 : (i - S_);
        const int jhi = (i + S_ > L_ - 1) ? (L_ - 1) : (i + S_);

        for (int j = jlo; j <= jhi; ++j) {
            const int r = j - (i0 - S_);      // LDS row, 0..95
            const int w = j - i + S_;         // 0..64
            const float4 vv = *(const float4*)&Vw[r][cq];

            float kx = 0.f, ky = 0.f, kz = 0.f, kw = 0.f;
            if (w != 0 && w != 2 * S_) {      // strict |rel| < S mask
                const float4 kk = *(const float4*)&Kw[r][cq];
                const float4 pp = *(const float4*)&Pw[w][cq];
                kx = kk.x + pp.x;
                ky = kk.y + pp.y;
                kz = kk.z + pp.z;
                kw = kk.w + pp.w;
            }
            const float e0 = __expf(qv.x * kx);
            const float e1 = __expf(qv.y * ky);
            const float e2 = __expf(qv.z * kz);
            const float e3 = __expf(qv.w * kw);
            den0 += e0; den1 += e1; den2 += e2; den3 += e3;
            num0 += e0 * vv.x; num1 += e1 * vv.y;
            num2 += e2 * vv.z; num3 += e3 * vv.w;
        }

        const float s0 = 1.f / (1.f + __expf(-qv.x));
        const float s1 = 1.f / (1.f + __expf(-qv.y));
        const float s2 = 1.f / (1.f + __expf(-qv.z));
        const float s3 = 1.f / (1.f + __expf(-qv.w));

        float4 o;
        o.x = s0 * s0 * num0 / den0;
        o.y = s1 * s1 * num1 / den1;
        o.z = s2 * s2 * num2 / den2;
        o.w = s3 * s3 * num3 / den3;
        *(float4*)(out + ((size_t)b * L_ + i) * E_ + c0 + cq) = o;
    }
}

// ===========================================================================
// PATH B (ws too small; fallback only): fully fused, fp32, from round 3.
// ===========================================================================
#define TI 32
#define CG 64
#define RK 96
#define LDP 68

__global__ __launch_bounds__(256) void aft_fused(
    const float* __restrict__ q,
    const float* __restrict__ Wq, const float* __restrict__ bq,
    const float* __restrict__ Wk, const float* __restrict__ bk,
    const float* __restrict__ Wv, const float* __restrict__ bv,
    const float* __restrict__ pb,
    float* __restrict__ out)
{
    __shared__ float Kl[RK][LDP];
    __shared__ float Vl[RK][LDP];
    __shared__ float Ql[TI][LDP];

    const int i0 = blockIdx.x * TI;
    const int b  = blockIdx.y;
    const int c0 = blockIdx.z * CG;

    const int wave = threadIdx.x >> 6;
    const int lane = threadIdx.x & 63;
    const int rsel = lane & 15;
    const int koff = (lane >> 4) * 8;

    const float* qb = q + (size_t)b * L_ * E_;

    for (int job = wave; job < 56; job += 4) {
        int p, rt, ct;
        if (job < 24)      { p = 0; rt = job >> 2;        ct = job & 3; }
        else if (job < 48) { p = 1; rt = (job - 24) >> 2; ct = (job - 24) & 3; }
        else               { p = 2; rt = (job - 48) >> 2; ct = (job - 48) & 3; }

        int jrow = (p == 2) ? (i0 + rt * 16 + rsel)
                            : (i0 - S_ + rt * 16 + rsel);
        int jc = jrow < 0 ? 0 : (jrow > L_ - 1 ? L_ - 1 : jrow);
        const float* pa = qb + (size_t)jc * E_ + koff;

        const float* Wm = (p == 0) ? Wk : (p == 1) ? Wv : Wq;
        const float* bm = (p == 0) ? bk : (p == 1) ? bv : bq;
        const int n = c0 + ct * 16 + rsel;
        const float* pw = Wm + (size_t)n * E_ + koff;

        f32x4 acc = {0.f, 0.f, 0.f, 0.f};
#pragma unroll
        for (int k0 = 0; k0 < 256; k0 += 32) {
            bf16x8 ah, al, bh, bl;
            load8split(pa + k0, ah, al);
            load8split(pw + k0, bh, bl);
            acc = __builtin_amdgcn_mfma_f32_16x16x32_bf16(ah, bh, acc, 0, 0, 0);
            acc = __builtin_amdgcn_mfma_f32_16x16x32_bf16(ah, bl, acc, 0, 0, 0);
            acc = __builtin_amdgcn_mfma_f32_16x16x32_bf16(al, bh, acc, 0, 0, 0);
        }

        const float bias = bm[n];
        const int row0 = rt * 16 + (lane >> 4) * 4;
        const int colc = ct * 16 + rsel;
        float* dst = (p == 0) ? &Kl[0][0] : (p == 1) ? &Vl[0][0] : &Ql[0][0];
#pragma unroll
        for (int r = 0; r < 4; ++r)
            dst[(size_t)(row0 + r) * LDP + colc] = acc[r] + bias;
    }
    __syncthreads();

    const int cq  = threadIdx.x & 15;
    const int is0 = threadIdx.x >> 4;
    const int cL  = cq * 4;
    const int cG  = c0 + cL;
    const float* pbc = pb + cG;

    for (int rr = is0; rr < TI; rr += 16) {
        const int i = i0 + rr;
        const float4 qv = *(const float4*)&Ql[rr][cL];

        float den0 = 0.f, den1 = 0.f, den2 = 0.f, den3 = 0.f;
        float num0 = 0.f, num1 = 0.f, num2 = 0.f, num3 = 0.f;

        const int jlo = (i - S_ < 0) ? 0 : (i - S_);
        const int jhi = (i + S_ > L_ - 1) ? (L_ - 1) : (i + S_);

        for (int j = jlo; j <= jhi; ++j) {
            const int r = j - (i0 - S_);
            const int w = j - i + S_;
            const float4 vv = *(const float4*)&Vl[r][cL];

            float kx = 0.f, ky = 0.f, kz = 0.f, kw = 0.f;
            if (w != 0 && w != 2 * S_) {
                const float4 kk = *(const float4*)&Kl[r][cL];
                const float4 pp = *(const float4*)(pbc + (size_t)w * E_);
                kx = kk.x + pp.x;
                ky = kk.y + pp.y;
                kz = kk.z + pp.z;
                kw = kk.w + pp.w;
            }
            const float e0 = __expf(qv.x * kx);
            const float e1 = __expf(qv.y * ky);
            const float e2 = __expf(qv.z * kz);
            const float e3 = __expf(qv.w * kw);
            den0 += e0; den1 += e1; den2 += e2; den3 += e3;
            num0 += e0 * vv.x; num1 += e1 * vv.y;
            num2 += e2 * vv.z; num3 += e3 * vv.w;
        }

        const float s0 = 1.f / (1.f + __expf(-qv.x));
        const float s1 = 1.f / (1.f + __expf(-qv.y));
        const float s2 = 1.f / (1.f + __expf(-qv.z));
        const float s3 = 1.f / (1.f + __expf(-qv.w));

        float4 o;
        o.x = s0 * s0 * num0 / den0;
        o.y = s1 * s1 * num1 / den1;
        o.z = s2 * s2 * num2 / den2;
        o.w = s3 * s3 * num3 / den3;
        *(float4*)(out + ((size_t)b * L_ + i) * E_ + cG) = o;
    }
}

extern "C" void kernel_launch(void* const* d_in, const int* in_sizes, int n_in,
                              void* d_out, int out_size, void* d_ws, size_t ws_size,
                              hipStream_t stream) {
    const float* q  = (const float*)d_in[0];
    const float* Wq = (const float*)d_in[1];
    const float* bq = (const float*)d_in[2];
    const float* Wk = (const float*)d_in[3];
    const float* bk = (const float*)d_in[4];
    const float* Wv = (const float*)d_in[5];
    const float* bv = (const float*)d_in[6];
    const float* pb = (const float*)d_in[7];

    const size_t needA = (size_t)3 * 4096 * 256 * sizeof(float);  // 12.6 MB

    if (ws_size >= needA) {
        float* Qf = (float*)d_ws;
        float* Kf = Qf + (size_t)4096 * 256;
        float* Vf = Kf + (size_t)4096 * 256;
        qkv_gemm2<<<dim3(128, 1, 3), 256, 0, stream>>>(q, Wq, bq, Wk, bk, Wv, bv,
                                                       Qf, Kf, Vf);
        aft_stage2b<<<dim3(L_ / TI2, B_, E_ / CH2), 256, 0, stream>>>(
            Qf, Kf, Vf, pb, (float*)d_out);
    } else {
        aft_fused<<<dim3(L_ / TI, B_, E_ / CG), 256, 0, stream>>>(
            q, Wq, bq, Wk, bk, Wv, bv, pb, (float*)d_out);
    }
}